// Round 5
// baseline (132.265 us; speedup 1.0000x reference)
//
#include <hip/hip_runtime.h>
#include <math.h>

// Problem constants (fixed by reference)
//  B=128, N=32, M=64, OBS=128, ACT=16, D_QK=128, D_AV=64, F_IN=144, H=64
// Outputs concatenated: value [B,32,32] @0, ret_weight [B,32,32] @131072,
// weight_other [B,32,64] @262144.
//
// Workspace (floats), 1,081,344 floats = 4.125 MB:
#define WS_WQK    0         // [128][128]
#define WS_WQKO   16384     // [128][128]
#define WS_AVAPRJ 32768     // [B][32][64]  avA @ W_f1a
#define WS_DPROJ  294912    // [B][32][64]  delta @ W_f1a
#define WS_AVOPRJ 557056    // [B][64][64]  avO @ W_f1b

#define INV_SQRT_DK 0.08838834764831845f  // 1/sqrt(128)

__device__ __forceinline__ float dot4(float4 a, float4 b) {
  return a.x*b.x + a.y*b.y + a.z*b.z + a.w*b.w;
}

// ---------------------------------------------------------------------------
// K1: independent pre-work. grid 416:
//   [0,32)    Wqk / Wqko fusion tiles (32x32 out each)
//   [32,160)  per b: avA/delta -> avAproj, dproj
//   [160,416) per (b, m-half): avO -> avOproj
// ---------------------------------------------------------------------------
__global__ __launch_bounds__(256) void k1_pre(
    const float* __restrict__ g_states, const float* __restrict__ g_pol,
    const float* __restrict__ g_act, const float* __restrict__ g_so,
    const float* __restrict__ g_ao,
    const float* __restrict__ Wq, const float* __restrict__ Wk,
    const float* __restrict__ Wqo, const float* __restrict__ Wko,
    const float* __restrict__ W_av, const float* __restrict__ W_avo,
    const float* __restrict__ W_f1, float* __restrict__ ws)
{
  __shared__ __align__(16) float pool[8576];   // 33.5 KB
  const int t = threadIdx.x;
  int blk = blockIdx.x;

  if (blk < 32) {
    // ---- weight fusion: Wqk[c][e] = sum_d Wq[c,d]*Wk[e,d] ----------------
    const float* A; const float* Bm; float* O;
    if (blk < 16) { A = Wq;  Bm = Wk;  O = ws + WS_WQK; }
    else          { A = Wqo; Bm = Wko; O = ws + WS_WQKO; blk -= 16; }
    const int tr = (blk >> 2) << 5;
    const int tc = (blk & 3) << 5;
    float* sA = pool;                 // [32][132]
    float* sB = pool + 4224;          // [32][132]
    const float4* a4 = (const float4*)(A + tr * 128);
    const float4* b4 = (const float4*)(Bm + tc * 128);
    #pragma unroll
    for (int u = 0; u < 4; ++u) {
      int f = t + u * 256;
      int r = f >> 5, c4 = f & 31;
      *(float4*)(sA + r*132 + c4*4) = a4[f];
      *(float4*)(sB + r*132 + c4*4) = b4[f];
    }
    __syncthreads();
    const int e = t & 31, cl0 = t >> 5;
    float acc[4] = {0,0,0,0};
    #pragma unroll 4
    for (int d4 = 0; d4 < 32; ++d4) {
      float4 bv = *(const float4*)(sB + e*132 + d4*4);
      #pragma unroll
      for (int rr = 0; rr < 4; ++rr) {
        float4 av = *(const float4*)(sA + (cl0 + rr*8)*132 + d4*4);
        acc[rr] += dot4(av, bv);
      }
    }
    #pragma unroll
    for (int rr = 0; rr < 4; ++rr)
      O[(tr + cl0 + rr*8)*128 + tc + e] = acc[rr];
    return;
  }
  blk -= 32;

  if (blk < 128) {
    // ---- per b: pre-acts -> avA, delta (LDS) -> avAproj, dproj (ws) ------
    const int b = blk;
    float* s_pre = pool;          // [32][132]: pre-act A at +0, P at +64
    float* s_av  = pool + 4224;   // avA   [32][68]
    float* s_dl  = pool + 6400;   // delta [32][68]
    {
      const int wv_  = t >> 6;          // wave 0..3
      const int ap   = wv_ & 1;         // 0 = actions, 1 = policies
      const int rh   = wv_ >> 1;        // row half (16 rows)
      const int lane = t & 63;          // d column
      const float* gs = g_states + b*4096 + rh*16*128;
      const float* gt = (ap ? g_pol : g_act) + b*512 + rh*16*16;
      float acc[16];
      #pragma unroll
      for (int r = 0; r < 16; ++r) acc[r] = 0.f;
      #pragma unroll 4
      for (int c4 = 0; c4 < 32; ++c4) {          // shared c < 128
        const float w0 = W_av[(c4*4+0)*64 + lane];
        const float w1 = W_av[(c4*4+1)*64 + lane];
        const float w2 = W_av[(c4*4+2)*64 + lane];
        const float w3 = W_av[(c4*4+3)*64 + lane];
        #pragma unroll
        for (int r = 0; r < 16; ++r) {
          float4 sv = *(const float4*)(gs + r*128 + c4*4);  // scalar (uniform)
          acc[r] += sv.x*w0 + sv.y*w1 + sv.z*w2 + sv.w*w3;
        }
      }
      #pragma unroll
      for (int c4 = 0; c4 < 4; ++c4) {           // tail c in [128,144)
        const float w0 = W_av[(128 + c4*4+0)*64 + lane];
        const float w1 = W_av[(128 + c4*4+1)*64 + lane];
        const float w2 = W_av[(128 + c4*4+2)*64 + lane];
        const float w3 = W_av[(128 + c4*4+3)*64 + lane];
        #pragma unroll
        for (int r = 0; r < 16; ++r) {
          float4 sv = *(const float4*)(gt + r*16 + c4*4);
          acc[r] += sv.x*w0 + sv.y*w1 + sv.z*w2 + sv.w*w3;
        }
      }
      #pragma unroll
      for (int r = 0; r < 16; ++r)
        s_pre[(rh*16 + r)*132 + ap*64 + lane] = acc[r];
    }
    __syncthreads();
    {
      const int r = t >> 3, d0 = (t & 7) << 3;
      float4 a0 = *(const float4*)(s_pre + r*132 + d0);
      float4 a1 = *(const float4*)(s_pre + r*132 + d0 + 4);
      float4 p0 = *(const float4*)(s_pre + r*132 + 64 + d0);
      float4 p1 = *(const float4*)(s_pre + r*132 + 64 + d0 + 4);
      float4 va0, va1, dl0, dl1;
      va0.x = tanhf(a0.x); va0.y = tanhf(a0.y); va0.z = tanhf(a0.z); va0.w = tanhf(a0.w);
      va1.x = tanhf(a1.x); va1.y = tanhf(a1.y); va1.z = tanhf(a1.z); va1.w = tanhf(a1.w);
      dl0.x = tanhf(p0.x) - va0.x; dl0.y = tanhf(p0.y) - va0.y;
      dl0.z = tanhf(p0.z) - va0.z; dl0.w = tanhf(p0.w) - va0.w;
      dl1.x = tanhf(p1.x) - va1.x; dl1.y = tanhf(p1.y) - va1.y;
      dl1.z = tanhf(p1.z) - va1.z; dl1.w = tanhf(p1.w) - va1.w;
      *(float4*)(s_av + r*68 + d0)     = va0;
      *(float4*)(s_av + r*68 + d0 + 4) = va1;
      *(float4*)(s_dl + r*68 + d0)     = dl0;
      *(float4*)(s_dl + r*68 + d0 + 4) = dl1;
    }
    __syncthreads();
    {
      // avAproj[j][h] = sum_d avA[j][d]*Wf1a[d][h]; dproj likewise w/ delta
      const int h = t & 63;
      const int j0 = (t >> 6) << 3;     // 8 rows per thread
      float da[8] = {0,0,0,0,0,0,0,0};
      float aa[8] = {0,0,0,0,0,0,0,0};
      #pragma unroll 4
      for (int d4 = 0; d4 < 16; ++d4) {
        float w0 = W_f1[(d4*4+0)*64 + h];
        float w1 = W_f1[(d4*4+1)*64 + h];
        float w2 = W_f1[(d4*4+2)*64 + h];
        float w3 = W_f1[(d4*4+3)*64 + h];
        #pragma unroll
        for (int q = 0; q < 8; ++q) {
          float4 dv = *(const float4*)(s_dl + (j0+q)*68 + d4*4);
          float4 av = *(const float4*)(s_av + (j0+q)*68 + d4*4);
          da[q] += dv.x*w0 + dv.y*w1 + dv.z*w2 + dv.w*w3;
          aa[q] += av.x*w0 + av.y*w1 + av.z*w2 + av.w*w3;
        }
      }
      #pragma unroll
      for (int q = 0; q < 8; ++q) {
        ws[WS_DPROJ  + b*2048 + (j0+q)*64 + h] = da[q];
        ws[WS_AVAPRJ + b*2048 + (j0+q)*64 + h] = aa[q];
      }
    }
    return;
  }
  blk -= 128;

  // ---- avO per (b, 32-row half) -> avOproj -------------------------------
  {
    const int b = blk >> 1, m0 = (blk & 1) << 5;
    float* s_avo = pool;          // [32][68]
    const int wv_  = t >> 6;            // 0..3: 8-row group
    const int lane = t & 63;
    const float* gso = g_so + (b*64 + m0 + wv_*8) * 128;
    const float* gao = g_ao + (b*64 + m0 + wv_*8) * 16;
    float acc[8];
    #pragma unroll
    for (int r = 0; r < 8; ++r) acc[r] = 0.f;
    #pragma unroll 4
    for (int c4 = 0; c4 < 32; ++c4) {
      const float w0 = W_avo[(c4*4+0)*64 + lane];
      const float w1 = W_avo[(c4*4+1)*64 + lane];
      const float w2 = W_avo[(c4*4+2)*64 + lane];
      const float w3 = W_avo[(c4*4+3)*64 + lane];
      #pragma unroll
      for (int r = 0; r < 8; ++r) {
        float4 sv = *(const float4*)(gso + r*128 + c4*4);  // scalar (uniform)
        acc[r] += sv.x*w0 + sv.y*w1 + sv.z*w2 + sv.w*w3;
      }
    }
    #pragma unroll
    for (int c4 = 0; c4 < 4; ++c4) {
      const float w0 = W_avo[(128 + c4*4+0)*64 + lane];
      const float w1 = W_avo[(128 + c4*4+1)*64 + lane];
      const float w2 = W_avo[(128 + c4*4+2)*64 + lane];
      const float w3 = W_avo[(128 + c4*4+3)*64 + lane];
      #pragma unroll
      for (int r = 0; r < 8; ++r) {
        float4 sv = *(const float4*)(gao + r*16 + c4*4);
        acc[r] += sv.x*w0 + sv.y*w1 + sv.z*w2 + sv.w*w3;
      }
    }
    #pragma unroll
    for (int r = 0; r < 8; ++r)
      s_avo[(wv_*8 + r)*68 + lane] = tanhf(acc[r]);
    __syncthreads();
    {
      // avOproj[m][h] = sum_d avO[m][d]*Wf1b[d][h]  (Wf1b = rows 64..127)
      const int h = t & 63;
      const int j0 = (t >> 6) << 3;
      float oa[8] = {0,0,0,0,0,0,0,0};
      #pragma unroll 4
      for (int d4 = 0; d4 < 16; ++d4) {
        float w0 = W_f1[(64 + d4*4+0)*64 + h];
        float w1 = W_f1[(64 + d4*4+1)*64 + h];
        float w2 = W_f1[(64 + d4*4+2)*64 + h];
        float w3 = W_f1[(64 + d4*4+3)*64 + h];
        #pragma unroll
        for (int q = 0; q < 8; ++q) {
          float4 ov = *(const float4*)(s_avo + (j0+q)*68 + d4*4);
          oa[q] += ov.x*w0 + ov.y*w1 + ov.z*w2 + ov.w*w3;
        }
      }
      #pragma unroll
      for (int q = 0; q < 8; ++q)
        ws[WS_AVOPRJ + b*4096 + (m0 + j0 + q)*64 + h] = oa[q];
    }
  }
}

// ---------------------------------------------------------------------------
// K2: main, per (b, i-octile). grid 512. LDS 12288 floats = 48 KB (3/CU):
//   A      @0     [4352]: states [32][132] / so tiles [32][132] / avOproj [64][68]
//   avAprj @4352  [2176]: [32][68]
//   dp     @6528  [2176]: [32][68]
//   P      @8704  [2144]: [8][268]  (P1 cols 0..127, P2 cols 128..255)
//   w      @10848 [288] : [8][36]
//   wo     @11136 [544] : [8][68]
//   base   @11680 [544] : [8][68]
//   wf2    @12224 [64]
// ---------------------------------------------------------------------------
__global__ __launch_bounds__(256) void k2_main(
    const float* __restrict__ g_states, const float* __restrict__ g_so,
    const float* __restrict__ ws, float* __restrict__ out,
    const float* __restrict__ W_f2)
{
  __shared__ __align__(16) float pool[12288];
  float* s_st   = pool;
  float* s_avOp = pool;            // alias A (after so tiles done)
  float* s_avAp = pool + 4352;
  float* s_dp   = pool + 6528;
  float* s_P    = pool + 8704;
  float* s_w    = pool + 10848;
  float* s_wo   = pool + 11136;
  float* s_base = pool + 11680;
  float* s_wf2  = pool + 12224;

  const int t = threadIdx.x;
  const int b = blockIdx.x >> 2;
  const int i0 = (blockIdx.x & 3) << 3;

  // ---- ph1: stage states, avAproj, dproj, wf2 ----------------------------
  {
    const float4* gs4 = (const float4*)(g_states + b * 4096);
    #pragma unroll
    for (int u = 0; u < 4; ++u) {
      int f = t + u * 256;
      int r = f >> 5, c4 = f & 31;
      *(float4*)(s_st + r*132 + c4*4) = gs4[f];
    }
    #pragma unroll
    for (int u = 0; u < 2; ++u) {
      int f = t + u * 256;                  // 0..511 float4
      int k = f >> 4, dq = f & 15;
      *(float4*)(s_avAp + k*68 + dq*4) = ((const float4*)(ws + WS_AVAPRJ + b*2048))[f];
      *(float4*)(s_dp   + k*68 + dq*4) = ((const float4*)(ws + WS_DPROJ  + b*2048))[f];
    }
    if (t < 16) *(float4*)(s_wf2 + t*4) = ((const float4*)W_f2)[t];
  }

  // ---- ph2: P = states[i0..+8] @ [Wqk|Wqko], register-resident -----------
  // wave = 64-col quarter of [P1|P2]; lane = col; 8 rows in regs; states
  // via scalar (uniform) loads; one coalesced b32 W-load per K-iter.
  {
    const int wv_ = t >> 6, lane = t & 63;
    const int cg  = wv_*64 + lane;               // global col 0..255
    const float* Wp = (wv_ < 2) ? (ws + WS_WQK  + cg)
                                : (ws + WS_WQKO + cg - 128);
    const float* srow = g_states + b*4096 + i0*128;
    float acc[8] = {0,0,0,0,0,0,0,0};
    #pragma unroll 4
    for (int c4 = 0; c4 < 32; ++c4) {
      float4 sv[8];
      #pragma unroll
      for (int r = 0; r < 8; ++r)
        sv[r] = *(const float4*)(srow + r*128 + c4*4);   // scalar (uniform)
      #pragma unroll
      for (int kk = 0; kk < 4; ++kk) {
        float wv = Wp[(c4*4 + kk)*128];
        #pragma unroll
        for (int r = 0; r < 8; ++r)
          acc[r] += wv * ((const float*)&sv[r])[kk];
      }
    }
    #pragma unroll
    for (int r = 0; r < 8; ++r)
      s_P[r*268 + cg] = acc[r];
  }
  __syncthreads();

  // ---- ph3: self scores + register softmax + write ret_weight ------------
  {
    const int r = t >> 5, j = t & 31;
    float acc = 0.f;
    #pragma unroll 8
    for (int e4 = 0; e4 < 32; ++e4) {
      float4 p4  = *(const float4*)(s_P + r*268 + e4*4);
      float4 st4 = *(const float4*)(s_st + j*132 + e4*4);
      acc += dot4(p4, st4);
    }
    acc *= INV_SQRT_DK;
    float mx = acc;
    for (int off = 16; off; off >>= 1) mx = fmaxf(mx, __shfl_xor(mx, off, 32));
    float ev = __expf(acc - mx);
    float sum = ev;
    for (int off = 16; off; off >>= 1) sum += __shfl_xor(sum, off, 32);
    float wn = ev / sum;
    out[131072 + b*1024 + (i0 + r)*32 + j] = wn;
    s_w[r*36 + j] = wn;
  }
  __syncthreads();

  // ---- ph4/5: other scores over two states_other tiles -------------------
  for (int tt = 0; tt < 2; ++tt) {
    const float4* gt4 = (const float4*)(g_so + (b*64 + tt*32) * 128);
    #pragma unroll
    for (int u = 0; u < 4; ++u) {
      int f = t + u * 256;
      int r = f >> 5, c4 = f & 31;
      *(float4*)(s_st + r*132 + c4*4) = gt4[f];
    }
    __syncthreads();
    const int r = t >> 5, m = t & 31;
    float acc = 0.f;
    #pragma unroll 8
    for (int c4 = 0; c4 < 32; ++c4) {
      float4 p4  = *(const float4*)(s_P + r*268 + 128 + c4*4);
      float4 st4 = *(const float4*)(s_st + m*132 + c4*4);
      acc += dot4(p4, st4);
    }
    s_wo[r*68 + tt*32 + m] = acc * INV_SQRT_DK;
    __syncthreads();
  }

  // ---- ph6: softmax wo + write weight_other; stage avOproj ---------------
  #pragma unroll
  for (int p = 0; p < 2; ++p) {
    const int r = (t >> 6) + (p << 2), l = t & 63;
    float v = s_wo[r*68 + l];
    float mx = v;
    for (int off = 32; off; off >>= 1) mx = fmaxf(mx, __shfl_xor(mx, off, 64));
    float ev = __expf(v - mx);
    float sum = ev;
    for (int off = 32; off; off >>= 1) sum += __shfl_xor(sum, off, 64);
    float wn = ev / sum;
    out[262144 + b*2048 + (i0 + r)*64 + l] = wn;
    s_wo[r*68 + l] = wn;
  }
  #pragma unroll
  for (int u = 0; u < 4; ++u) {
    int f = t + u * 256;
    int m = f >> 4, dq = f & 15;
    *(float4*)(s_avOp + m*68 + dq*4) = ((const float4*)(ws + WS_AVOPRJ + b*4096))[f];
  }
  __syncthreads();

  // ---- ph7: base[i][h] = sum_k w[i,k]avAproj[k,h] + sum_m wo[i,m]avOproj[m,h]
  {
    const int g = t >> 6, h = t & 63;
    const int r0 = g*2, r1 = r0 + 1;
    float a0 = 0.f, a1 = 0.f;
    #pragma unroll 2
    for (int k4 = 0; k4 < 8; ++k4) {
      float4 wa = *(const float4*)(s_w + r0*36 + k4*4);   // uniform
      float4 wb = *(const float4*)(s_w + r1*36 + k4*4);
      #pragma unroll
      for (int kk = 0; kk < 4; ++kk) {
        float pv = s_avAp[(k4*4 + kk)*68 + h];
        a0 += ((const float*)&wa)[kk] * pv;
        a1 += ((const float*)&wb)[kk] * pv;
      }
    }
    #pragma unroll 2
    for (int m4 = 0; m4 < 16; ++m4) {
      float4 wa = *(const float4*)(s_wo + r0*68 + m4*4);  // uniform
      float4 wb = *(const float4*)(s_wo + r1*68 + m4*4);
      #pragma unroll
      for (int kk = 0; kk < 4; ++kk) {
        float pv = s_avOp[(m4*4 + kk)*68 + h];
        a0 += ((const float*)&wa)[kk] * pv;
        a1 += ((const float*)&wb)[kk] * pv;
      }
    }
    s_base[r0*68 + h] = a0;
    s_base[r1*68 + h] = a1;
  }
  __syncthreads();

  // ---- ph9: value[i][j] = sum_h lrelu(base[i,h]+w[i,j]*dproj[j,h])*Wf2[h] -
  {
    const int i = t >> 5, j = t & 31;
    const float wij = s_w[i*36 + j];
    float acc = 0.f;
    #pragma unroll 4
    for (int hq = 0; hq < 16; ++hq) {
      float4 b4 = *(const float4*)(s_base + i*68 + hq*4);
      float4 d4 = *(const float4*)(s_dp + j*68 + hq*4);
      float4 f4 = *(const float4*)(s_wf2 + hq*4);
      float p0 = b4.x + wij*d4.x; p0 = p0 > 0.f ? p0 : 0.01f*p0;
      float p1 = b4.y + wij*d4.y; p1 = p1 > 0.f ? p1 : 0.01f*p1;
      float p2 = b4.z + wij*d4.z; p2 = p2 > 0.f ? p2 : 0.01f*p2;
      float p3 = b4.w + wij*d4.w; p3 = p3 > 0.f ? p3 : 0.01f*p3;
      acc += p0*f4.x + p1*f4.y + p2*f4.z + p3*f4.w;
    }
    out[b*1024 + (i0 + i)*32 + j] = acc;
  }
}

extern "C" void kernel_launch(void* const* d_in, const int* in_sizes, int n_in,
                              void* d_out, int out_size, void* d_ws, size_t ws_size,
                              hipStream_t stream) {
  const float* states        = (const float*)d_in[0];
  const float* policies      = (const float*)d_in[1];
  const float* actions       = (const float*)d_in[2];
  const float* states_other  = (const float*)d_in[3];
  const float* actions_other = (const float*)d_in[4];
  const float* W_key         = (const float*)d_in[5];
  const float* W_query       = (const float*)d_in[6];
  const float* W_av          = (const float*)d_in[7];
  const float* W_key_other   = (const float*)d_in[8];
  const float* W_query_other = (const float*)d_in[9];
  const float* W_av_other    = (const float*)d_in[10];
  const float* W_f1          = (const float*)d_in[11];
  const float* W_f2          = (const float*)d_in[12];
  float* out = (float*)d_out;
  float* ws  = (float*)d_ws;   // 4.125 MB used

  k1_pre<<<416, 256, 0, stream>>>(states, policies, actions, states_other,
                                  actions_other, W_query, W_key,
                                  W_query_other, W_key_other, W_av, W_av_other,
                                  W_f1, ws);
  k2_main<<<512, 256, 0, stream>>>(states, states_other, ws, out, W_f2);
}